// Round 5
// baseline (129.687 us; speedup 1.0000x reference)
//
#include <hip/hip_runtime.h>
#include <hip/hip_bf16.h>

// TopKPooling, MI355X. Fixed shapes: B=256 graphs x 256 nodes, C=256,
// on_index = even in-graph nodes (128/graph, M=32768), ratio=k=16.
// perm = per-graph top-16 N/O atoms by (score desc, id asc).
// d_out FLOAT32: x_top[1048576] | perm[4096] | score_on[32768] | on_index[32768].
// Uniform per-element threshold 1310.72 -> bf16 MFMA scoring safe.
// Timing floor: two ~41us harness d_ws poison fills live inside the timed
// window (~82us fixed); controllable part is mlp (+pack+topk_gather).

typedef __attribute__((ext_vector_type(8))) short short8v;
typedef __attribute__((ext_vector_type(4))) float float4v;

// ws layout (bytes):
#define W1P_OFF 0         // 16 ntile x 8 kstep x 64 lane x 8 bf16 = 131072 B
#define W2P_OFF 131072    //  8 x 8 x 64 x 8 x 2 = 65536 B
#define W3P_OFF 196608    //  4 x 4 x 64 x 8 x 2 = 16384 B
#define SCORES_OFF 212992 // 32768 f32   (total 344064 B)

static __device__ __forceinline__ float lrelu(float z) { return z > 0.0f ? z : 0.1f * z; }

static __device__ __forceinline__ short f2bf(float f) {
    union { float f; unsigned u; } v; v.f = f;
    const unsigned r = v.u + 0x7FFFu + ((v.u >> 16) & 1u);   // round-nearest-even
    return (short)(r >> 16);
}

// Swizzled offset (in shorts) into a [32][256] bf16 LDS tile.
// 16B chunks XOR'd by row&7 -> ds_read_b128 A-frag loads hit all 32 banks
// uniformly (2 lanes/bank = free), row stride 512B (no pad -> 32KB total).
static __device__ __forceinline__ int sw_off(int row, int chunk, int within) {
    return row * 256 + ((chunk ^ (row & 7)) << 3) + within;
}

// Pack W1/W2/W3 into MFMA B-fragment order: unit = (ntile,kstep); within unit,
// lane l holds B[k = (l>>4)*8 + j][n = nt*16 + (l&15)], j=0..7 -> 16B contiguous.
__global__ __launch_bounds__(256) void pack_kernel(
    const float* __restrict__ W1, const float* __restrict__ W2,
    const float* __restrict__ W3, short* __restrict__ ws)
{
    const int u = blockIdx.x * 256 + threadIdx.x;
    if (u >= 13312) return;
    const float* W; int N, unitBase, uu;
    short* dst;
    if (u < 8192)       { W = W1; N = 256; uu = u;         dst = ws + (W1P_OFF/2); unitBase = 8; }
    else if (u < 12288) { W = W2; N = 128; uu = u - 8192;  dst = ws + (W2P_OFF/2); unitBase = 8; }
    else                { W = W3; N = 64;  uu = u - 12288; dst = ws + (W3P_OFF/2); unitBase = 4; }
    const int perNt = unitBase * 64;
    const int nt   = uu / perNt;
    const int rem  = uu % perNt;
    const int ks   = rem / 64;
    const int lane = rem % 64;
    const int q = lane >> 4;
    const int n = nt * 16 + (lane & 15);
    short8v frag;
    #pragma unroll
    for (int j = 0; j < 8; ++j) {
        const int k = ks * 32 + q * 8 + j;
        frag[j] = f2bf(W[(size_t)k * N + n]);
    }
    *(short8v*)(dst + (size_t)uu * 8) = frag;
}

// Fused 3-layer MLP + score, bf16 MFMA (16x16x32). 32 rows/block, 4 waves.
// 32KB LDS + VGPR<=102 (launch_bounds 256,5) -> 5 blocks/CU, 5 waves/SIMD.
__global__ __launch_bounds__(256, 5) void mlp_score_kernel(
    const float* __restrict__ x, const float* __restrict__ pe,
    const float* __restrict__ b1, const float* __restrict__ b2,
    const float* __restrict__ b3, const float* __restrict__ w_atom,
    const int* __restrict__ on_index, const short* __restrict__ ws_pack,
    float* __restrict__ ws_scores,
    float* __restrict__ out_score, float* __restrict__ out_onidx)
{
    __shared__ __align__(16) short XP[32 * 256];  // xp bf16 -> h2 bf16 -> score partials(f32)
    __shared__ __align__(16) short H1[32 * 256];  // h1 bf16 -> h3 f32
    const int t   = threadIdx.x;
    const int m0  = blockIdx.x * 32;
    const int wid = t >> 6;
    const int lane = t & 63;
    const int q = lane >> 4;       // quad 0..3
    const int c = lane & 15;       // col-in-tile / row-in-tile for A

    const short* W1p = ws_pack + (W1P_OFF / 2);
    const short* W2p = ws_pack + (W2P_OFF / 2);
    const short* W3p = ws_pack + (W3P_OFF / 2);

    // ---- stage xp = bf16(x[node] + pe[node&255]) into XP (swizzled) ----
    #pragma unroll
    for (int i = 0; i < 4; ++i) {
        const int u = t + i * 256;        // 0..1023
        const int r = u >> 5;             // row 0..31
        const int ck = u & 31;            // 16B chunk 0..31
        const int k = ck << 3;            // col base
        const int node = on_index[m0 + r];
        const float4 xa = *(const float4*)(x + (size_t)node * 256 + k);
        const float4 xb = *(const float4*)(x + (size_t)node * 256 + k + 4);
        const float4 pa = *(const float4*)(pe + (size_t)(node & 255) * 256 + k);
        const float4 pb = *(const float4*)(pe + (size_t)(node & 255) * 256 + k + 4);
        short8v s;
        s[0] = f2bf(xa.x + pa.x); s[1] = f2bf(xa.y + pa.y);
        s[2] = f2bf(xa.z + pa.z); s[3] = f2bf(xa.w + pa.w);
        s[4] = f2bf(xb.x + pb.x); s[5] = f2bf(xb.y + pb.y);
        s[6] = f2bf(xb.z + pb.z); s[7] = f2bf(xb.w + pb.w);
        *(short8v*)(&XP[sw_off(r, ck, 0)]) = s;
    }
    __syncthreads();

    // ---- layer 1: h1 = lrelu(xp @ W1 + b1)  [32 x 256] ----
    // wave -> 4 ntiles x 2 mtiles, split into 2 passes of 2 ntiles (reg cap).
    #pragma unroll
    for (int g = 0; g < 2; ++g) {
        const int ntA = wid * 4 + g * 2;
        float4v acc[2][2];
        #pragma unroll
        for (int nt = 0; nt < 2; ++nt) {
            const float bb = b1[(ntA + nt) * 16 + c];
            acc[0][nt] = (float4v){bb, bb, bb, bb};
            acc[1][nt] = (float4v){bb, bb, bb, bb};
        }
        #pragma unroll
        for (int ks = 0; ks < 8; ++ks) {
            const short8v a0 = *(const short8v*)(&XP[sw_off(c,      ks * 4 + q, 0)]);
            const short8v a1 = *(const short8v*)(&XP[sw_off(16 + c, ks * 4 + q, 0)]);
            #pragma unroll
            for (int nt = 0; nt < 2; ++nt) {
                const short8v b = *(const short8v*)(W1p + ((size_t)((ntA + nt) * 8 + ks) * 64 + lane) * 8);
                acc[0][nt] = __builtin_amdgcn_mfma_f32_16x16x32_bf16(a0, b, acc[0][nt], 0, 0, 0);
                acc[1][nt] = __builtin_amdgcn_mfma_f32_16x16x32_bf16(a1, b, acc[1][nt], 0, 0, 0);
            }
        }
        // epilogue: C/D map col=lane&15, row=q*4+r
        #pragma unroll
        for (int mt = 0; mt < 2; ++mt)
            #pragma unroll
            for (int nt = 0; nt < 2; ++nt)
                #pragma unroll
                for (int r = 0; r < 4; ++r) {
                    const int row = mt * 16 + q * 4 + r;
                    const int col = (ntA + nt) * 16 + c;
                    H1[sw_off(row, col >> 3, col & 7)] = f2bf(lrelu(acc[mt][nt][r]));
                }
    }
    __syncthreads();

    // ---- layer 2: h2 = lrelu(h1 @ W2 + b2)  [32 x 128], wave -> 2 ntiles x 2 mtiles ----
    {
        const int nt0 = wid * 2;
        float4v acc[2][2];
        #pragma unroll
        for (int nt = 0; nt < 2; ++nt) {
            const float bb = b2[(nt0 + nt) * 16 + c];
            acc[0][nt] = (float4v){bb, bb, bb, bb};
            acc[1][nt] = (float4v){bb, bb, bb, bb};
        }
        #pragma unroll
        for (int ks = 0; ks < 8; ++ks) {
            const short8v a0 = *(const short8v*)(&H1[sw_off(c,      ks * 4 + q, 0)]);
            const short8v a1 = *(const short8v*)(&H1[sw_off(16 + c, ks * 4 + q, 0)]);
            #pragma unroll
            for (int nt = 0; nt < 2; ++nt) {
                const short8v b = *(const short8v*)(W2p + ((size_t)((nt0 + nt) * 8 + ks) * 64 + lane) * 8);
                acc[0][nt] = __builtin_amdgcn_mfma_f32_16x16x32_bf16(a0, b, acc[0][nt], 0, 0, 0);
                acc[1][nt] = __builtin_amdgcn_mfma_f32_16x16x32_bf16(a1, b, acc[1][nt], 0, 0, 0);
            }
        }
        __syncthreads();  // all layer-1 reads of XP done grid... block-wide; XP now dead
        #pragma unroll
        for (int mt = 0; mt < 2; ++mt)
            #pragma unroll
            for (int nt = 0; nt < 2; ++nt)
                #pragma unroll
                for (int r = 0; r < 4; ++r) {
                    const int row = mt * 16 + q * 4 + r;
                    const int col = (nt0 + nt) * 16 + c;   // < 128 -> chunk < 16
                    XP[sw_off(row, col >> 3, col & 7)] = f2bf(lrelu(acc[mt][nt][r]));
                }
    }
    __syncthreads();

    // ---- layer 3: h3 = lrelu(h2 @ W3 + b3)  [32 x 64], wave -> 1 ntile x 2 mtiles ----
    {
        const int nt = wid;
        float4v acc[2];
        const float bb = b3[nt * 16 + c];
        acc[0] = (float4v){bb, bb, bb, bb};
        acc[1] = (float4v){bb, bb, bb, bb};
        #pragma unroll
        for (int ks = 0; ks < 4; ++ks) {
            const short8v a0 = *(const short8v*)(&XP[sw_off(c,      ks * 4 + q, 0)]);
            const short8v a1 = *(const short8v*)(&XP[sw_off(16 + c, ks * 4 + q, 0)]);
            const short8v b = *(const short8v*)(W3p + ((size_t)(nt * 4 + ks) * 64 + lane) * 8);
            acc[0] = __builtin_amdgcn_mfma_f32_16x16x32_bf16(a0, b, acc[0], 0, 0, 0);
            acc[1] = __builtin_amdgcn_mfma_f32_16x16x32_bf16(a1, b, acc[1], 0, 0, 0);
        }
        // h3 as f32 into H1 (last H1 read was layer-2 MFMA, pre-barrier -> safe)
        float* H3F = (float*)H1;   // [32][68] f32 = 8704 B <= 16384
        #pragma unroll
        for (int mt = 0; mt < 2; ++mt)
            #pragma unroll
            for (int r = 0; r < 4; ++r)
                H3F[(mt * 16 + q * 4 + r) * 68 + nt * 16 + c] = lrelu(acc[mt][r]);
    }
    __syncthreads();

    // ---- score = tanh((h3 . w_atom) / ||w_atom||) ----
    {
        const float* H3F = (const float*)H1;
        float* PART = (float*)XP;  // XP's last read was layer-3 MFMA, pre-barrier -> safe
        const int r = t >> 3, p = t & 7;
        float s = 0.0f;
        #pragma unroll
        for (int j = 0; j < 8; ++j) s += H3F[r * 68 + p * 8 + j] * w_atom[p * 8 + j];
        PART[t] = s;
        __syncthreads();
        if (t < 32) {
            float sum = 0.0f;
            #pragma unroll
            for (int pp = 0; pp < 8; ++pp) sum += PART[t * 8 + pp];
            float n2 = 0.0f;
            for (int cc = 0; cc < 64; ++cc) { const float w = w_atom[cc]; n2 += w * w; }
            const float sc = tanhf(sum / sqrtf(n2));
            const int m = m0 + t;
            ws_scores[m] = sc;
            out_score[m] = sc;
            out_onidx[m] = (float)on_index[m];
        }
    }
}

// Fused: per-graph exact stable top-16 (rank counting: score desc, id asc)
// + gather x_top[g][k][:] = (x[node] + pe[node&255]) * score[node]  (fp32 exact).
__global__ __launch_bounds__(256) void topk_gather_kernel(
    const float* __restrict__ x, const float* __restrict__ pe,
    const float* __restrict__ ws_scores, const int* __restrict__ on_index,
    float* __restrict__ out_perm, float* __restrict__ out_xtop)
{
    __shared__ float s[128];
    __shared__ int   sel_node[16];
    __shared__ float sel_sc[16];
    const int g = blockIdx.x, t = threadIdx.x;
    if (t < 128) s[t] = ws_scores[g * 128 + t];
    __syncthreads();
    if (t < 128) {
        const float sj = s[t];
        int rank = 0;
        for (int i = 0; i < 128; ++i) {
            const float si = s[i];
            rank += (si > sj) || (si == sj && i < t);
        }
        if (rank < 16) {
            const int node = on_index[g * 128 + t];
            sel_node[rank] = node;
            sel_sc[rank]   = sj;
            out_perm[g * 16 + rank] = (float)node;
        }
    }
    __syncthreads();
    #pragma unroll
    for (int k = 0; k < 16; ++k) {
        const int node = sel_node[k];
        const float sc = sel_sc[k];
        const float v = (x[(size_t)node * 256 + t] + pe[(size_t)(node & 255) * 256 + t]) * sc;
        out_xtop[((size_t)(g * 16 + k)) * 256 + t] = v;
    }
}

extern "C" void kernel_launch(void* const* d_in, const int* in_sizes, int n_in,
                              void* d_out, int out_size, void* d_ws, size_t ws_size,
                              hipStream_t stream)
{
    const float* x   = (const float*)d_in[0];
    const float* pe  = (const float*)d_in[1];
    const float* W1  = (const float*)d_in[2];
    const float* b1  = (const float*)d_in[3];
    const float* W2  = (const float*)d_in[4];
    const float* b2  = (const float*)d_in[5];
    const float* W3  = (const float*)d_in[6];
    const float* b3  = (const float*)d_in[7];
    const float* wa  = (const float*)d_in[8];
    const int* on_index = (const int*)d_in[10];

    float* out = (float*)d_out;
    float* out_xtop  = out;
    float* out_perm  = out + 1048576;
    float* out_score = out + 1048576 + 4096;
    float* out_onidx = out + 1048576 + 4096 + 32768;

    short* ws_pack   = (short*)d_ws;
    float* ws_scores = (float*)((char*)d_ws + SCORES_OFF);

    hipLaunchKernelGGL(pack_kernel, dim3(52), dim3(256), 0, stream, W1, W2, W3, ws_pack);
    hipLaunchKernelGGL(mlp_score_kernel, dim3(1024), dim3(256), 0, stream,
                       x, pe, b1, b2, b3, wa, on_index, (const short*)ws_pack,
                       ws_scores, out_score, out_onidx);
    hipLaunchKernelGGL(topk_gather_kernel, dim3(256), dim3(256), 0, stream,
                       x, pe, ws_scores, on_index, out_perm, out_xtop);
}

// Round 6
// 126.094 us; speedup vs baseline: 1.0285x; 1.0285x over previous
//
#include <hip/hip_runtime.h>
#include <hip/hip_bf16.h>

// TopKPooling, MI355X. Fixed shapes: B=256 graphs x 256 nodes, C=256,
// on_index = even in-graph nodes (128/graph, M=32768), ratio=k=16.
// perm = per-graph top-16 N/O atoms by (score desc, id asc).
// d_out FLOAT32: x_top[1048576] | perm[4096] | score_on[32768] | on_index[32768].
// Uniform per-element threshold 1310.72 -> bf16 MFMA scoring safe.
// Harness floor: two ~41us poison fills + d_in restore live in the timed window.
// R6 change: TM=64 rows/block, 512 thr (8 waves) -> W L2 traffic halved
// (213->106 MB), each B-frag feeds 4 mtiles (2x MFMA per W load).

typedef __attribute__((ext_vector_type(8))) short short8v;
typedef __attribute__((ext_vector_type(4))) float float4v;

// ws layout (bytes):
#define W1P_OFF 0         // 16 ntile x 8 kstep x 64 lane x 8 bf16 = 131072 B
#define W2P_OFF 131072    //  8 x 8 x 64 x 8 x 2 = 65536 B
#define W3P_OFF 196608    //  4 x 4 x 64 x 8 x 2 = 16384 B
#define SCORES_OFF 212992 // 32768 f32   (total 344064 B)

static __device__ __forceinline__ float lrelu(float z) { return z > 0.0f ? z : 0.1f * z; }

static __device__ __forceinline__ short f2bf(float f) {
    union { float f; unsigned u; } v; v.f = f;
    const unsigned r = v.u + 0x7FFFu + ((v.u >> 16) & 1u);   // round-nearest-even
    return (short)(r >> 16);
}

// Swizzled offset (in shorts) into a [64][256] bf16 LDS tile.
// 16B chunks XOR'd by row&7 -> b128 A-frag reads hit all 32 banks (2 lanes/bank).
static __device__ __forceinline__ int sw_off(int row, int chunk, int within) {
    return row * 256 + ((chunk ^ (row & 7)) << 3) + within;
}

// Pack W1/W2/W3 into MFMA B-fragment order: unit = (ntile,kstep); within unit,
// lane l holds B[k = (l>>4)*8 + j][n = nt*16 + (l&15)], j=0..7 -> 16B contiguous.
__global__ __launch_bounds__(256) void pack_kernel(
    const float* __restrict__ W1, const float* __restrict__ W2,
    const float* __restrict__ W3, short* __restrict__ ws)
{
    const int u = blockIdx.x * 256 + threadIdx.x;
    if (u >= 13312) return;
    const float* W; int N, unitBase, uu;
    short* dst;
    if (u < 8192)       { W = W1; N = 256; uu = u;         dst = ws + (W1P_OFF/2); unitBase = 8; }
    else if (u < 12288) { W = W2; N = 128; uu = u - 8192;  dst = ws + (W2P_OFF/2); unitBase = 8; }
    else                { W = W3; N = 64;  uu = u - 12288; dst = ws + (W3P_OFF/2); unitBase = 4; }
    const int perNt = unitBase * 64;
    const int nt   = uu / perNt;
    const int rem  = uu % perNt;
    const int ks   = rem / 64;
    const int lane = rem % 64;
    const int q = lane >> 4;
    const int n = nt * 16 + (lane & 15);
    short8v frag;
    #pragma unroll
    for (int j = 0; j < 8; ++j) {
        const int k = ks * 32 + q * 8 + j;
        frag[j] = f2bf(W[(size_t)k * N + n]);
    }
    *(short8v*)(dst + (size_t)uu * 8) = frag;
}

// Fused 3-layer MLP + score, bf16 MFMA (16x16x32). 64 rows/block, 8 waves.
// 64KB LDS -> 2 blocks/CU (4 waves/SIMD); grid 512 = exactly one round.
__global__ __launch_bounds__(512, 4) void mlp_score_kernel(
    const float* __restrict__ x, const float* __restrict__ pe,
    const float* __restrict__ b1, const float* __restrict__ b2,
    const float* __restrict__ b3, const float* __restrict__ w_atom,
    const int* __restrict__ on_index, const short* __restrict__ ws_pack,
    float* __restrict__ ws_scores,
    float* __restrict__ out_score, float* __restrict__ out_onidx)
{
    __shared__ __align__(16) short XP[64 * 256];  // xp bf16 -> h2 bf16 -> partials f32
    __shared__ __align__(16) short H1[64 * 256];  // h1 bf16 -> h3 f32
    const int t   = threadIdx.x;
    const int m0  = blockIdx.x * 64;
    const int wid = t >> 6;        // 0..7
    const int lane = t & 63;
    const int q = lane >> 4;       // quad 0..3
    const int c = lane & 15;       // col-in-tile / row-in-tile for A

    const short* W1p = ws_pack + (W1P_OFF / 2);
    const short* W2p = ws_pack + (W2P_OFF / 2);
    const short* W3p = ws_pack + (W3P_OFF / 2);

    // ---- stage xp = bf16(x[node] + pe[node&255]) into XP (swizzled) ----
    #pragma unroll
    for (int i = 0; i < 4; ++i) {
        const int u = t + i * 512;        // 0..2047
        const int r = u >> 5;             // row 0..63
        const int ck = u & 31;            // 16B chunk 0..31
        const int k = ck << 3;            // col base
        const int node = on_index[m0 + r];
        const float4 xa = *(const float4*)(x + (size_t)node * 256 + k);
        const float4 xb = *(const float4*)(x + (size_t)node * 256 + k + 4);
        const float4 pa = *(const float4*)(pe + (size_t)(node & 255) * 256 + k);
        const float4 pb = *(const float4*)(pe + (size_t)(node & 255) * 256 + k + 4);
        short8v s;
        s[0] = f2bf(xa.x + pa.x); s[1] = f2bf(xa.y + pa.y);
        s[2] = f2bf(xa.z + pa.z); s[3] = f2bf(xa.w + pa.w);
        s[4] = f2bf(xb.x + pb.x); s[5] = f2bf(xb.y + pb.y);
        s[6] = f2bf(xb.z + pb.z); s[7] = f2bf(xb.w + pb.w);
        *(short8v*)(&XP[sw_off(r, ck, 0)]) = s;
    }
    __syncthreads();

    // ---- layer 1: h1 = lrelu(xp @ W1 + b1)  [64 x 256] ----
    // wave -> 2 ntiles x 4 mtiles, 2 passes of 1 ntile (reg cap); B-frag
    // loaded once per (nt,ks), reused across 4 mtiles.
    #pragma unroll
    for (int g = 0; g < 2; ++g) {
        const int nt = wid * 2 + g;
        float4v acc[4];
        const float bb = b1[nt * 16 + c];
        #pragma unroll
        for (int mt = 0; mt < 4; ++mt) acc[mt] = (float4v){bb, bb, bb, bb};
        #pragma unroll
        for (int ks = 0; ks < 8; ++ks) {
            const short8v b = *(const short8v*)(W1p + ((size_t)(nt * 8 + ks) * 64 + lane) * 8);
            #pragma unroll
            for (int mt = 0; mt < 4; ++mt) {
                const short8v a = *(const short8v*)(&XP[sw_off(mt * 16 + c, ks * 4 + q, 0)]);
                acc[mt] = __builtin_amdgcn_mfma_f32_16x16x32_bf16(a, b, acc[mt], 0, 0, 0);
            }
        }
        // epilogue: C/D map col=lane&15, row=q*4+r
        #pragma unroll
        for (int mt = 0; mt < 4; ++mt)
            #pragma unroll
            for (int r = 0; r < 4; ++r) {
                const int row = mt * 16 + q * 4 + r;
                const int col = nt * 16 + c;
                H1[sw_off(row, col >> 3, col & 7)] = f2bf(lrelu(acc[mt][r]));
            }
    }
    __syncthreads();

    // ---- layer 2: h2 = lrelu(h1 @ W2 + b2)  [64 x 128], wave -> 1 ntile x 4 mtiles ----
    {
        const int nt = wid;   // 0..7
        float4v acc[4];
        const float bb = b2[nt * 16 + c];
        #pragma unroll
        for (int mt = 0; mt < 4; ++mt) acc[mt] = (float4v){bb, bb, bb, bb};
        #pragma unroll
        for (int ks = 0; ks < 8; ++ks) {
            const short8v b = *(const short8v*)(W2p + ((size_t)(nt * 8 + ks) * 64 + lane) * 8);
            #pragma unroll
            for (int mt = 0; mt < 4; ++mt) {
                const short8v a = *(const short8v*)(&H1[sw_off(mt * 16 + c, ks * 4 + q, 0)]);
                acc[mt] = __builtin_amdgcn_mfma_f32_16x16x32_bf16(a, b, acc[mt], 0, 0, 0);
            }
        }
        // XP (xp) dead since barrier-1 -> overwrite with h2 (cols < 128)
        #pragma unroll
        for (int mt = 0; mt < 4; ++mt)
            #pragma unroll
            for (int r = 0; r < 4; ++r) {
                const int row = mt * 16 + q * 4 + r;
                const int col = nt * 16 + c;
                XP[sw_off(row, col >> 3, col & 7)] = f2bf(lrelu(acc[mt][r]));
            }
    }
    __syncthreads();

    // ---- layer 3: h3 = lrelu(h2 @ W3 + b3)  [64 x 64] ----
    // 8 waves -> nt = wid&3, mtile pair = (wid>>2)*2.
    {
        const int nt  = wid & 3;
        const int mt0 = (wid >> 2) * 2;
        float4v acc[2];
        const float bb = b3[nt * 16 + c];
        acc[0] = (float4v){bb, bb, bb, bb};
        acc[1] = (float4v){bb, bb, bb, bb};
        #pragma unroll
        for (int ks = 0; ks < 4; ++ks) {
            const short8v b = *(const short8v*)(W3p + ((size_t)(nt * 4 + ks) * 64 + lane) * 8);
            const short8v a0 = *(const short8v*)(&XP[sw_off((mt0 + 0) * 16 + c, ks * 4 + q, 0)]);
            const short8v a1 = *(const short8v*)(&XP[sw_off((mt0 + 1) * 16 + c, ks * 4 + q, 0)]);
            acc[0] = __builtin_amdgcn_mfma_f32_16x16x32_bf16(a0, b, acc[0], 0, 0, 0);
            acc[1] = __builtin_amdgcn_mfma_f32_16x16x32_bf16(a1, b, acc[1], 0, 0, 0);
        }
        // h3 f32 into H1 (H1 last read = layer-2 MFMA, pre-barrier-2 -> safe):
        float* H3F = (float*)H1;   // [64][68] f32 = 17408 B <= 32768
        #pragma unroll
        for (int mt = 0; mt < 2; ++mt)
            #pragma unroll
            for (int r = 0; r < 4; ++r)
                H3F[((mt0 + mt) * 16 + q * 4 + r) * 68 + nt * 16 + c] = lrelu(acc[mt][r]);
    }
    __syncthreads();

    // ---- score = tanh((h3 . w_atom) / ||w_atom||) ----
    {
        const float* H3F = (const float*)H1;
        float* PART = (float*)XP;  // XP last read = layer-3 MFMA, pre-barrier-3 -> safe
        const int r = t >> 3, p = t & 7;   // 64 rows x 8 partial lanes
        float s = 0.0f;
        #pragma unroll
        for (int j = 0; j < 8; ++j) s += H3F[r * 68 + p * 8 + j] * w_atom[p * 8 + j];
        PART[t] = s;
        __syncthreads();
        if (t < 64) {
            float sum = 0.0f;
            #pragma unroll
            for (int pp = 0; pp < 8; ++pp) sum += PART[t * 8 + pp];
            float n2 = 0.0f;
            for (int cc = 0; cc < 64; ++cc) { const float w = w_atom[cc]; n2 += w * w; }
            const float sc = tanhf(sum / sqrtf(n2));
            const int m = m0 + t;
            ws_scores[m] = sc;
            out_score[m] = sc;
            out_onidx[m] = (float)on_index[m];
        }
    }
}

// Fused: per-graph exact stable top-16 (rank counting: score desc, id asc)
// + gather x_top[g][k][:] = (x[node] + pe[node&255]) * score[node]  (fp32 exact).
__global__ __launch_bounds__(256) void topk_gather_kernel(
    const float* __restrict__ x, const float* __restrict__ pe,
    const float* __restrict__ ws_scores, const int* __restrict__ on_index,
    float* __restrict__ out_perm, float* __restrict__ out_xtop)
{
    __shared__ float s[128];
    __shared__ int   sel_node[16];
    __shared__ float sel_sc[16];
    const int g = blockIdx.x, t = threadIdx.x;
    if (t < 128) s[t] = ws_scores[g * 128 + t];
    __syncthreads();
    if (t < 128) {
        const float sj = s[t];
        int rank = 0;
        for (int i = 0; i < 128; ++i) {
            const float si = s[i];
            rank += (si > sj) || (si == sj && i < t);
        }
        if (rank < 16) {
            const int node = on_index[g * 128 + t];
            sel_node[rank] = node;
            sel_sc[rank]   = sj;
            out_perm[g * 16 + rank] = (float)node;
        }
    }
    __syncthreads();
    #pragma unroll
    for (int k = 0; k < 16; ++k) {
        const int node = sel_node[k];
        const float sc = sel_sc[k];
        const float v = (x[(size_t)node * 256 + t] + pe[(size_t)(node & 255) * 256 + t]) * sc;
        out_xtop[((size_t)(g * 16 + k)) * 256 + t] = v;
    }
}

extern "C" void kernel_launch(void* const* d_in, const int* in_sizes, int n_in,
                              void* d_out, int out_size, void* d_ws, size_t ws_size,
                              hipStream_t stream)
{
    const float* x   = (const float*)d_in[0];
    const float* pe  = (const float*)d_in[1];
    const float* W1  = (const float*)d_in[2];
    const float* b1  = (const float*)d_in[3];
    const float* W2  = (const float*)d_in[4];
    const float* b2  = (const float*)d_in[5];
    const float* W3  = (const float*)d_in[6];
    const float* b3  = (const float*)d_in[7];
    const float* wa  = (const float*)d_in[8];
    const int* on_index = (const int*)d_in[10];

    float* out = (float*)d_out;
    float* out_xtop  = out;
    float* out_perm  = out + 1048576;
    float* out_score = out + 1048576 + 4096;
    float* out_onidx = out + 1048576 + 4096 + 32768;

    short* ws_pack   = (short*)d_ws;
    float* ws_scores = (float*)((char*)d_ws + SCORES_OFF);

    hipLaunchKernelGGL(pack_kernel, dim3(52), dim3(256), 0, stream, W1, W2, W3, ws_pack);
    hipLaunchKernelGGL(mlp_score_kernel, dim3(512), dim3(512), 0, stream,
                       x, pe, b1, b2, b3, wa, on_index, (const short*)ws_pack,
                       ws_scores, out_score, out_onidx);
    hipLaunchKernelGGL(topk_gather_kernel, dim3(256), dim3(256), 0, stream,
                       x, pe, ws_scores, on_index, out_perm, out_xtop);
}